// Round 1
// baseline (135.905 us; speedup 1.0000x reference)
//
#include <hip/hip_runtime.h>

// HumanComposer3D: per-pixel composite over K=8 layers.
// texels: (B,H,W,8,5) f32  [r,g,b,a,label]
// zbuf:   (B,H,W,8)   f32
// bkg:    (3,)        f32
// out (concat, f32): image (npix*4) | depth (npix) | label (npix) | human (npix*8*4)

__global__ __launch_bounds__(256) void composer_kernel(
    const float* __restrict__ texels,
    const float* __restrict__ zbuf,
    const float* __restrict__ bkg,
    float* __restrict__ out,
    int npix)
{
    int pix = blockIdx.x * 256 + threadIdx.x;
    if (pix >= npix) return;

    const float bk0 = bkg[0], bk1 = bkg[1], bk2 = bkg[2];

    // ---- load this pixel's 40 texel floats (10x float4, 16B aligned) ----
    float t[40];
    {
        const float4* tp = reinterpret_cast<const float4*>(texels + (size_t)pix * 40);
        #pragma unroll
        for (int i = 0; i < 10; ++i) {
            float4 v = tp[i];
            t[4*i+0] = v.x; t[4*i+1] = v.y; t[4*i+2] = v.z; t[4*i+3] = v.w;
        }
    }
    // ---- load 8 zbuf floats (2x float4) ----
    float z[8];
    {
        const float4* zp = reinterpret_cast<const float4*>(zbuf + (size_t)pix * 8);
        float4 v0 = zp[0];
        float4 v1 = zp[1];
        z[0]=v0.x; z[1]=v0.y; z[2]=v0.z; z[3]=v0.w;
        z[4]=v1.x; z[5]=v1.y; z[6]=v1.z; z[7]=v1.w;
    }

    // ---- compositing scan, k = 7 .. 0 (matches reference's reversed scan) ----
    float r = bk0, g = bk1, b = bk2;
    float a = 0.0f, d = 100.0f, l = 8.0f;
    #pragma unroll
    for (int k = 7; k >= 0; --k) {
        const float lr = t[5*k+0], lg = t[5*k+1], lb = t[5*k+2];
        const float la = t[5*k+3], ll = t[5*k+4];
        const float zd = z[k];
        const float om = 1.0f - la;
        r = fmaf(lr, la, r * om);
        g = fmaf(lg, la, g * om);
        b = fmaf(lb, la, b * om);
        a = fmaxf(la, a);
        if (zd > 0.0f)  d = fmaf(zd, la, d * om);
        if (zd >= 0.0f) l = (la > 0.5f) ? ll : l;
    }

    // ---- integer labels per layer (exact small ints in fp32) ----
    int li[8];
    #pragma unroll
    for (int k = 0; k < 8; ++k)
        li[k] = (z[k] >= 0.0f) ? __float2int_rn(t[5*k+4]) : -1;

    // ---- write composite image / depth / label ----
    const size_t np = (size_t)npix;
    reinterpret_cast<float4*>(out)[pix] = make_float4(r, g, b, a);
    out[np*4 + pix] = d;
    out[np*5 + pix] = (l > 7.5f) ? -1.0f : (float)__float2int_rn(l);

    // ---- human images: per class n, first layer k (ascending) with label n ----
    float4* o_h = reinterpret_cast<float4*>(out + np*6) + (size_t)pix * 8;
    #pragma unroll
    for (int n = 0; n < 8; ++n) {
        float cr = 0.0f, cg = 0.0f, cb = 0.0f, ca = 0.0f;
        bool found = false;
        #pragma unroll
        for (int k = 0; k < 8; ++k) {
            bool m = (!found) && (li[k] == n);
            if (m) { cr = t[5*k+0]; cg = t[5*k+1]; cb = t[5*k+2]; ca = t[5*k+3]; found = true; }
        }
        const float oma = 1.0f - ca;
        o_h[n] = make_float4(fmaf(cr, ca, bk0 * oma),
                             fmaf(cg, ca, bk1 * oma),
                             fmaf(cb, ca, bk2 * oma),
                             ca);
    }
}

extern "C" void kernel_launch(void* const* d_in, const int* in_sizes, int n_in,
                              void* d_out, int out_size, void* d_ws, size_t ws_size,
                              hipStream_t stream) {
    const float* texels = (const float*)d_in[0];
    const float* zbuf   = (const float*)d_in[1];
    const float* bkg    = (const float*)d_in[2];
    float* out = (float*)d_out;

    const int npix = in_sizes[1] / 8;           // B*H*W from zbuf element count
    const int blocks = (npix + 255) / 256;
    hipLaunchKernelGGL(composer_kernel, dim3(blocks), dim3(256), 0, stream,
                       texels, zbuf, bkg, out, npix);
}

// Round 3
// 68.556 us; speedup vs baseline: 1.9824x; 1.9824x over previous
//
#include <hip/hip_runtime.h>

// HumanComposer3D: per-pixel composite over K=8 layers, LDS-staged for coalescing.
// texels: (B,H,W,8,5) f32  [r,g,b,a,label]
// zbuf:   (B,H,W,8)   f32
// bkg:    (3,)        f32
// out (concat, f32): image (npix*4) | depth (npix) | label (npix) | human (npix*8*4)

#define TPAD 41   // texel LDS pixel stride in words; 41%32=9, gcd(9,32)=1 -> conflict-free reads
#define HPAD 33   // human LDS pixel stride in words; conflict-free writes

typedef float vf4 __attribute__((ext_vector_type(4)));   // nontemporal-store-compatible

__global__ __launch_bounds__(256) void composer_kernel(
    const float* __restrict__ texels,
    const float* __restrict__ zbuf,
    const float* __restrict__ bkg,
    float* __restrict__ out,
    int npix)
{
    __shared__ float lds[256 * TPAD];   // 41,984 B; reused for human staging (256*33 words)

    const int tid  = threadIdx.x;
    const int base = blockIdx.x * 256;          // first pixel of this block
    const bool full = (base + 256 <= npix);
    const float bk0 = bkg[0], bk1 = bkg[1], bk2 = bkg[2];
    const size_t np = (size_t)npix;

    float t[40];
    float z[8];
    int   pix = base + tid;

    if (full) {
        // ---- phase 1: cooperative coalesced global->LDS texel load ----
        const float4* gt = reinterpret_cast<const float4*>(texels) + (size_t)base * 10;
        #pragma unroll
        for (int i = 0; i < 10; ++i) {
            int idx = i * 256 + tid;        // float4 index within block
            float4 v = gt[idx];
            int p  = idx / 10;              // pixel within block
            int f4 = idx % 10;
            float* d = &lds[p * TPAD + f4 * 4];
            d[0] = v.x; d[1] = v.y; d[2] = v.z; d[3] = v.w;
        }
        __syncthreads();

        // ---- phase 2: LDS -> registers (conflict-free, stride 41) ----
        {
            const float* s = &lds[tid * TPAD];
            #pragma unroll
            for (int e = 0; e < 40; ++e) t[e] = s[e];
        }
        {
            const float4* zp = reinterpret_cast<const float4*>(zbuf + (size_t)pix * 8);
            float4 v0 = zp[0], v1 = zp[1];
            z[0]=v0.x; z[1]=v0.y; z[2]=v0.z; z[3]=v0.w;
            z[4]=v1.x; z[5]=v1.y; z[6]=v1.z; z[7]=v1.w;
        }
        __syncthreads();   // all LDS reads done before human staging overwrites
    } else {
        // tail block (not hit for 768x768x2, but keep correct): direct loads
        if (pix < npix) {
            const float4* tp = reinterpret_cast<const float4*>(texels + (size_t)pix * 40);
            #pragma unroll
            for (int i = 0; i < 10; ++i) {
                float4 v = tp[i];
                t[4*i+0]=v.x; t[4*i+1]=v.y; t[4*i+2]=v.z; t[4*i+3]=v.w;
            }
            const float4* zp = reinterpret_cast<const float4*>(zbuf + (size_t)pix * 8);
            float4 v0 = zp[0], v1 = zp[1];
            z[0]=v0.x; z[1]=v0.y; z[2]=v0.z; z[3]=v0.w;
            z[4]=v1.x; z[5]=v1.y; z[6]=v1.z; z[7]=v1.w;
        }
    }

    const bool active = full || (pix < npix);
    if (active) {
        // ---- compositing scan, k = 7..0 ----
        float r = bk0, g = bk1, b = bk2;
        float a = 0.0f, d = 100.0f, l = 8.0f;
        #pragma unroll
        for (int k = 7; k >= 0; --k) {
            const float lr = t[5*k+0], lg = t[5*k+1], lb = t[5*k+2];
            const float la = t[5*k+3], ll = t[5*k+4];
            const float zd = z[k];
            const float om = 1.0f - la;
            r = fmaf(lr, la, r * om);
            g = fmaf(lg, la, g * om);
            b = fmaf(lb, la, b * om);
            a = fmaxf(la, a);
            if (zd > 0.0f)  d = fmaf(zd, la, d * om);
            if (zd >= 0.0f) l = (la > 0.5f) ? ll : l;
        }

        // composite image / depth / label (coalesced, nontemporal)
        {
            vf4 img = { r, g, b, a };
            __builtin_nontemporal_store(img, reinterpret_cast<vf4*>(out) + pix);
            __builtin_nontemporal_store(d, out + np*4 + pix);
            const float lo = (l > 7.5f) ? -1.0f : (float)__float2int_rn(l);
            __builtin_nontemporal_store(lo, out + np*5 + pix);
        }

        // ---- per-layer integer labels ----
        int li[8];
        #pragma unroll
        for (int k = 0; k < 8; ++k)
            li[k] = (z[k] >= 0.0f) ? __float2int_rn(t[5*k+4]) : -1;

        // ---- human images ----
        if (full) {
            // stage to LDS (stride 33: conflict-free writes)
            float* hb = &lds[tid * HPAD];
            #pragma unroll
            for (int n = 0; n < 8; ++n) {
                float cr=0.f, cg=0.f, cb=0.f, ca=0.f; bool found=false;
                #pragma unroll
                for (int k = 0; k < 8; ++k) {
                    bool m = (!found) && (li[k] == n);
                    if (m) { cr=t[5*k+0]; cg=t[5*k+1]; cb=t[5*k+2]; ca=t[5*k+3]; found=true; }
                }
                const float oma = 1.0f - ca;
                hb[n*4+0] = fmaf(cr, ca, bk0 * oma);
                hb[n*4+1] = fmaf(cg, ca, bk1 * oma);
                hb[n*4+2] = fmaf(cb, ca, bk2 * oma);
                hb[n*4+3] = ca;
            }
        } else {
            vf4* o_h = reinterpret_cast<vf4*>(out + np*6) + (size_t)pix * 8;
            #pragma unroll
            for (int n = 0; n < 8; ++n) {
                float cr=0.f, cg=0.f, cb=0.f, ca=0.f; bool found=false;
                #pragma unroll
                for (int k = 0; k < 8; ++k) {
                    bool m = (!found) && (li[k] == n);
                    if (m) { cr=t[5*k+0]; cg=t[5*k+1]; cb=t[5*k+2]; ca=t[5*k+3]; found=true; }
                }
                const float oma = 1.0f - ca;
                vf4 h = { fmaf(cr,ca,bk0*oma), fmaf(cg,ca,bk1*oma),
                          fmaf(cb,ca,bk2*oma), ca };
                __builtin_nontemporal_store(h, o_h + n);
            }
        }
    }

    if (full) {
        __syncthreads();
        // ---- phase 3b: cooperative coalesced LDS->global human store ----
        vf4* gh = reinterpret_cast<vf4*>(out + np*6) + (size_t)base * 8;
        #pragma unroll
        for (int i = 0; i < 8; ++i) {
            int idx = i * 256 + tid;        // float4 index within block region
            int P = idx >> 3;               // pixel within block
            int c = idx & 7;                // float4 within pixel
            const float* s = &lds[P * HPAD + c * 4];
            vf4 h = { s[0], s[1], s[2], s[3] };
            __builtin_nontemporal_store(h, gh + idx);
        }
    }
}

extern "C" void kernel_launch(void* const* d_in, const int* in_sizes, int n_in,
                              void* d_out, int out_size, void* d_ws, size_t ws_size,
                              hipStream_t stream) {
    const float* texels = (const float*)d_in[0];
    const float* zbuf   = (const float*)d_in[1];
    const float* bkg    = (const float*)d_in[2];
    float* out = (float*)d_out;

    const int npix = in_sizes[1] / 8;           // B*H*W from zbuf element count
    const int blocks = (npix + 255) / 256;
    hipLaunchKernelGGL(composer_kernel, dim3(blocks), dim3(256), 0, stream,
                       texels, zbuf, bkg, out, npix);
}